// Round 11
// baseline (170.063 us; speedup 1.0000x reference)
//
#include <hip/hip_runtime.h>
#include <math.h>

#define B 8192
#define D 128
#define C 1000
#define EPS 1e-6f
#define LAMBD 0.1f

// ws layout (float slots):
// [0] ce_acc [1] (unused)
// [2        .. 2+B)    dtot[i]            (zeroed by k_rowstats)
// [2+B      .. 2+2B)   e[i] = sq+2*EPS*s
// [2+2B     .. 2+3B)   f[j] = sq-2*EPS*s
// [2+3B     .. 2+4B)   dpos[i]
// [2+4B     .. +C)     fo[c] as unsigned  (memset 0xFF; unsigned atomicMin)
// [33792    .. +B*64)  xbf: x as bf16, linear row-major 16B chunks
#define OFF_DTOT 2
#define OFF_E (2 + B)
#define OFF_F (2 + 2 * B)
#define OFF_DPOS (2 + 3 * B)
#define OFF_FO (2 + 4 * B)
#define OFF_XBF 33792

typedef __attribute__((ext_vector_type(8))) short short8;
typedef __attribute__((ext_vector_type(4))) float floatx4;

__device__ inline unsigned short f2bf(float f) {
    union { float f; unsigned u; } v; v.f = f;
    unsigned u = v.u;
    return (unsigned short)((u + 0x7fffu + ((u >> 16) & 1u)) >> 16);  // RTNE
}

// one wave per row: stats + linear bf16 copy of x + dtot zeroing
__global__ void __launch_bounds__(256)
k_rowstats(const float* __restrict__ x, const int* __restrict__ y, float* ws) {
    int row = blockIdx.x * 4 + (threadIdx.x >> 6);
    int lane = threadIdx.x & 63;
    const float2* x2 = (const float2*)x;
    float2 v = x2[row * 64 + lane];  // elements 2*lane, 2*lane+1
    float sq = v.x * v.x + v.y * v.y;
    float s = v.x + v.y;
    for (int o = 32; o; o >>= 1) {
        sq += __shfl_xor(sq, o);
        s += __shfl_xor(s, o);
    }
    ushort2 p = { f2bf(v.x), f2bf(v.y) };
    ushort2* xrow = (ushort2*)((unsigned short*)(ws + OFF_XBF) + row * 128);
    xrow[lane] = p;  // linear, coalesced
    if (lane == 0) {
        ws[OFF_E + row] = sq + 2.f * EPS * s;
        ws[OFF_F + row] = sq - 2.f * EPS * s;
        atomicMin((unsigned*)(ws + OFF_FO) + y[row], (unsigned)row);
    }
    if (lane == 1) ws[OFF_DTOT + row] = 0.f;
    if (blockIdx.x == 0 && threadIdx.x == 0) ws[0] = 0.f;
}

// wave-per-row CE: 4 rows / 256-thread block, no barriers in the hot path.
__global__ void __launch_bounds__(256)
k_ce(const float* __restrict__ data, const int* __restrict__ y, float* ws) {
    int row = blockIdx.x * 4 + (threadIdx.x >> 6);
    int lane = threadIdx.x & 63;
    const float* dr = data + (size_t)row * C;
    const float4* dr4 = (const float4*)dr;  // row*4000B is 16B-aligned

    float4 v[4];
    float m = -1e30f;
#pragma unroll
    for (int k = 0; k < 4; k++) {
        int idx = k * 64 + lane;
        if (idx < C / 4) {
            v[k] = dr4[idx];
            m = fmaxf(fmaxf(fmaxf(m, v[k].x), fmaxf(v[k].y, v[k].z)), v[k].w);
        }
    }
    for (int o = 32; o; o >>= 1) m = fmaxf(m, __shfl_xor(m, o));

    float sum = 0.f;
#pragma unroll
    for (int k = 0; k < 4; k++) {
        int idx = k * 64 + lane;
        if (idx < C / 4) {
            sum += __expf(v[k].x - m) + __expf(v[k].y - m) +
                   __expf(v[k].z - m) + __expf(v[k].w - m);
        }
    }
    for (int o = 32; o; o >>= 1) sum += __shfl_xor(sum, o);

    __shared__ float sp[4];
    if (lane == 0) {
        float lse = m + __logf(sum);
        sp[threadIdx.x >> 6] = lse - dr[y[row]];
    }
    __syncthreads();
    if (threadIdx.x == 0)
        atomicAdd(ws + 0, sp[0] + sp[1] + sp[2] + sp[3]);
}

__global__ void k_dpos(const float* __restrict__ x, const int* __restrict__ y,
                       float* ws) {
    int row = blockIdx.x * 4 + (threadIdx.x >> 6);
    int lane = threadIdx.x & 63;
    const unsigned* fo = (const unsigned*)(ws + OFF_FO);
    int fp = (int)fo[y[row]];
    float d0 = x[row * D + lane] - x[fp * D + lane] + EPS;
    float d1 = x[row * D + 64 + lane] - x[fp * D + 64 + lane] + EPS;
    float sq = d0 * d0 + d1 * d1;
    for (int o = 32; o; o >>= 1) sq += __shfl_xor(sq, o);
    if (lane == 0) ws[OFF_DPOS + row] = sqrtf(sq);
}

// Gram + dist + row/col sums via MFMA. Register-resident, LDS-free, no barriers,
// no cross-tile register state (keeps VGPR low -> 3 blocks/CU).
// Triangular pairing: pair p = {band p, band 63-p} = 65 j-tiles, split over
// 24 sub-blocks -> grid 768. A/B frags streamed from L2 (xbf = 2MB, L2-hot).
__global__ void __launch_bounds__(256, 3)
k_gram_dtot(float* ws) {
    const int t = threadIdx.x;
    const int lane = t & 63, wid = t >> 6;
    const int wm = wid >> 1, wn = wid & 1;
    const int lo = lane & 15, hi = lane >> 4;
    const int p = blockIdx.x / 24;
    const int sub = blockIdx.x % 24;
    const int b0 = p, b1 = 63 - p;
    const int n0 = 64 - b0;

    const short8* __restrict__ xb8 = (const short8*)(ws + OFF_XBF);
    const float* __restrict__ e = ws + OFF_E;
    const float* __restrict__ f = ws + OFF_F;
    float* dtot = ws + OFF_DTOT;
    const float deps2 = (float)D * EPS * EPS;

    for (int q = sub; q < 65; q += 24) {
        const int band = (q < n0) ? b0 : b1;
        const int j = (q < n0) ? b0 + q : b1 + (q - n0);
        const int ar = band * 128 + wm * 64;
        const int jr = j * 128 + wn * 64;

        floatx4 acc[4][4];
#pragma unroll
        for (int mr = 0; mr < 4; ++mr)
#pragma unroll
            for (int nr = 0; nr < 4; ++nr)
                acc[mr][nr] = (floatx4){0.f, 0.f, 0.f, 0.f};

#pragma unroll
        for (int kt = 0; kt < 4; ++kt) {
            const int ch = kt * 4 + hi;
            short8 af[4], bg[4];
#pragma unroll
            for (int mr = 0; mr < 4; ++mr)
                af[mr] = xb8[(ar + mr * 16 + lo) * 16 + ch];
#pragma unroll
            for (int nr = 0; nr < 4; ++nr)
                bg[nr] = xb8[(jr + nr * 16 + lo) * 16 + ch];
#pragma unroll
            for (int mr = 0; mr < 4; ++mr)
#pragma unroll
                for (int nr = 0; nr < 4; ++nr)
                    acc[mr][nr] = __builtin_amdgcn_mfma_f32_16x16x32_bf16(
                        af[mr], bg[nr], acc[mr][nr], 0, 0, 0);
        }

        float er[4][4], fc[4];
#pragma unroll
        for (int mr = 0; mr < 4; ++mr)
#pragma unroll
            for (int rg = 0; rg < 4; ++rg)
                er[mr][rg] = e[ar + mr * 16 + hi * 4 + rg] + deps2;
#pragma unroll
        for (int nr = 0; nr < 4; ++nr) fc[nr] = f[jr + nr * 16 + lo];

        float rs[4][4];
        float cs[4] = {0.f, 0.f, 0.f, 0.f};
#pragma unroll
        for (int mr = 0; mr < 4; ++mr)
#pragma unroll
            for (int rg = 0; rg < 4; ++rg) rs[mr][rg] = 0.f;

#pragma unroll
        for (int mr = 0; mr < 4; ++mr)
#pragma unroll
            for (int nr = 0; nr < 4; ++nr)
#pragma unroll
                for (int rg = 0; rg < 4; ++rg) {
                    float d2 = fmaf(-2.f, acc[mr][nr][rg], er[mr][rg]) + fc[nr];
                    float pp = fmaxf(d2, deps2);
                    float d = pp * __frsqrt_rn(pp);  // sqrt via v_rsq
                    rs[mr][rg] += d;
                    cs[nr] += d;
                }

        // row sums -> dtot[band rows]
#pragma unroll
        for (int mr = 0; mr < 4; ++mr)
#pragma unroll
            for (int rg = 0; rg < 4; ++rg) {
                float v = rs[mr][rg];
                v += __shfl_xor(v, 1);
                v += __shfl_xor(v, 2);
                v += __shfl_xor(v, 4);
                v += __shfl_xor(v, 8);
                if (lo == 0) atomicAdd(&dtot[ar + mr * 16 + hi * 4 + rg], v);
            }
        // col sums -> dtot[j rows] (skip diagonal tile: rows already cover it)
        if (j != band) {
#pragma unroll
            for (int nr = 0; nr < 4; ++nr) {
                float v = cs[nr];
                v += __shfl_xor(v, 16);
                v += __shfl_xor(v, 32);
                if (hi == 0) atomicAdd(&dtot[jr + nr * 16 + lo], v);
            }
        }
    }
}

// fused feature-loss reduce + final output (single block)
__global__ void __launch_bounds__(1024)
k_featout(const float* __restrict__ ws, float* __restrict__ out) {
    int t = threadIdx.x;
    const float* dtot = ws + OFF_DTOT;
    const float* dpos = ws + OFF_DPOS;
    float r = 0.f;
#pragma unroll
    for (int k = 0; k < B / 1024; k++) {
        int i = k * 1024 + t;
        float dp = dpos[i], dt = dtot[i];
        r += dp / (dt - dp);
    }
    for (int o = 32; o; o >>= 1) r += __shfl_xor(r, o);
    __shared__ float sm[16];
    if ((t & 63) == 0) sm[t >> 6] = r;
    __syncthreads();
    if (t == 0) {
        float lf = 0.f;
#pragma unroll
        for (int w = 0; w < 16; w++) lf += sm[w];
        float la = ws[0] / (float)B;
        out[0] = la + LAMBD * lf;
        out[1] = la;
        out[2] = lf;
    }
}

extern "C" void kernel_launch(void* const* d_in, const int* in_sizes, int n_in,
                              void* d_out, int out_size, void* d_ws, size_t ws_size,
                              hipStream_t stream) {
    const float* data = (const float*)d_in[0];
    const float* x = (const float*)d_in[1];
    const int* y = (const int*)d_in[2];
    float* out = (float*)d_out;
    float* ws = (float*)d_ws;

    (void)hipMemsetAsync(ws + OFF_FO, 0xFF, C * sizeof(unsigned), stream);  // fo
    k_rowstats<<<B / 4, 256, 0, stream>>>(x, y, ws);
    k_ce<<<B / 4, 256, 0, stream>>>(data, y, ws);
    k_dpos<<<B / 4, 256, 0, stream>>>(x, y, ws);
    k_gram_dtot<<<768, 256, 0, stream>>>(ws);
    k_featout<<<1, 1024, 0, stream>>>(ws, out);
}

// Round 13
// 161.689 us; speedup vs baseline: 1.0518x; 1.0518x over previous
//
#include <hip/hip_runtime.h>
#include <math.h>

#define B 8192
#define D 128
#define C 1000
#define EPS 1e-6f
#define LAMBD 0.1f

// ws layout (float slots):
// [0] ce_acc
// [16       .. 16+B)   dtot[i]            (zeroed by k_rowstats)
// [16+B     .. 16+2B)  e[i] = sq+2*EPS*s  (16B-aligned base)
// [16+2B    .. 16+3B)  f[j] = sq-2*EPS*s
// [16+3B    .. 16+4B)  dpos[i]
// [16+4B    .. +C)     fo[c] as unsigned  (memset 0xFF; unsigned atomicMin)
// [33792    .. +B*64)  xbf: x as bf16, linear row-major 16B chunks
#define OFF_DTOT 16
#define OFF_E (16 + B)
#define OFF_F (16 + 2 * B)
#define OFF_DPOS (16 + 3 * B)
#define OFF_FO (16 + 4 * B)
#define OFF_XBF 33792

typedef __attribute__((ext_vector_type(8))) short short8;
typedef __attribute__((ext_vector_type(4))) float floatx4;

__device__ inline unsigned short f2bf(float f) {
    union { float f; unsigned u; } v; v.f = f;
    unsigned u = v.u;
    return (unsigned short)((u + 0x7fffu + ((u >> 16) & 1u)) >> 16);  // RTNE
}

// one wave per row: stats + linear bf16 copy of x + dtot zeroing
__global__ void __launch_bounds__(256)
k_rowstats(const float* __restrict__ x, const int* __restrict__ y, float* ws) {
    int row = blockIdx.x * 4 + (threadIdx.x >> 6);
    int lane = threadIdx.x & 63;
    const float2* x2 = (const float2*)x;
    float2 v = x2[row * 64 + lane];
    float sq = v.x * v.x + v.y * v.y;
    float s = v.x + v.y;
    for (int o = 32; o; o >>= 1) {
        sq += __shfl_xor(sq, o);
        s += __shfl_xor(s, o);
    }
    ushort2 p = { f2bf(v.x), f2bf(v.y) };
    ushort2* xrow = (ushort2*)((unsigned short*)(ws + OFF_XBF) + row * 128);
    xrow[lane] = p;  // linear, coalesced
    if (lane == 0) {
        ws[OFF_E + row] = sq + 2.f * EPS * s;
        ws[OFF_F + row] = sq - 2.f * EPS * s;
        atomicMin((unsigned*)(ws + OFF_FO) + y[row], (unsigned)row);
    }
    if (lane == 1) ws[OFF_DTOT + row] = 0.f;
    if (blockIdx.x == 0 && threadIdx.x == 0) ws[0] = 0.f;
}

// wave-per-row CE: 4 rows / 256-thread block, no barriers in the hot path.
__global__ void __launch_bounds__(256)
k_ce(const float* __restrict__ data, const int* __restrict__ y, float* ws) {
    int row = blockIdx.x * 4 + (threadIdx.x >> 6);
    int lane = threadIdx.x & 63;
    const float* dr = data + (size_t)row * C;
    const float4* dr4 = (const float4*)dr;

    float4 v[4];
    float m = -1e30f;
#pragma unroll
    for (int k = 0; k < 4; k++) {
        int idx = k * 64 + lane;
        if (idx < C / 4) {
            v[k] = dr4[idx];
            m = fmaxf(fmaxf(fmaxf(m, v[k].x), fmaxf(v[k].y, v[k].z)), v[k].w);
        }
    }
    for (int o = 32; o; o >>= 1) m = fmaxf(m, __shfl_xor(m, o));

    float sum = 0.f;
#pragma unroll
    for (int k = 0; k < 4; k++) {
        int idx = k * 64 + lane;
        if (idx < C / 4) {
            sum += __expf(v[k].x - m) + __expf(v[k].y - m) +
                   __expf(v[k].z - m) + __expf(v[k].w - m);
        }
    }
    for (int o = 32; o; o >>= 1) sum += __shfl_xor(sum, o);

    __shared__ float sp[4];
    if (lane == 0) {
        float lse = m + __logf(sum);
        sp[threadIdx.x >> 6] = lse - dr[y[row]];
    }
    __syncthreads();
    if (threadIdx.x == 0)
        atomicAdd(ws + 0, sp[0] + sp[1] + sp[2] + sp[3]);
}

__global__ void k_dpos(const float* __restrict__ x, const int* __restrict__ y,
                       float* ws) {
    int row = blockIdx.x * 4 + (threadIdx.x >> 6);
    int lane = threadIdx.x & 63;
    const unsigned* fo = (const unsigned*)(ws + OFF_FO);
    int fp = (int)fo[y[row]];
    float d0 = x[row * D + lane] - x[fp * D + lane] + EPS;
    float d1 = x[row * D + 64 + lane] - x[fp * D + 64 + lane] + EPS;
    float sq = d0 * d0 + d1 * d1;
    for (int o = 32; o; o >>= 1) sq += __shfl_xor(sq, o);
    if (lane == 0) ws[OFF_DPOS + row] = sqrtf(sq);
}

// Gram + dist + row/col sums via MFMA. Register-resident, LDS-free, no barriers.
// Software-pipelined: bg double-buffer across kt; next tile's kt0 + e/f loads
// issue before the long sqrt epilogue (hides L2 latency under VALU work).
// A-frags cached in regs per band (band switch <=1 per block).
__global__ void __launch_bounds__(256)
k_gram_dtot(float* ws) {
    const int t = threadIdx.x;
    const int lane = t & 63, wid = t >> 6;
    const int wm = wid >> 1, wn = wid & 1;
    const int lo = lane & 15, hi = lane >> 4;
    const int p = blockIdx.x >> 4;    // pair 0..31
    const int sub = blockIdx.x & 15;  // 0..15
    const int b0 = p, b1 = 63 - p;
    const int n0 = 64 - b0;

    const short8* __restrict__ xb8 = (const short8*)(ws + OFF_XBF);
    const float* __restrict__ e = ws + OFF_E;
    const float* __restrict__ f = ws + OFF_F;
    float* dtot = ws + OFF_DTOT;
    const float deps2 = (float)D * EPS * EPS;

    short8 af[4][4];   // [kt][mr], cached per band
    short8 bgs[2][4];  // double-buffered B frags
    float rs[4][4];

#define FLUSH_RS()                                                            \
    {                                                                         \
        _Pragma("unroll") for (int mr = 0; mr < 4; ++mr)                      \
            _Pragma("unroll") for (int rg = 0; rg < 4; ++rg) {                \
            float v = rs[mr][rg];                                             \
            v += __shfl_xor(v, 1);                                            \
            v += __shfl_xor(v, 2);                                            \
            v += __shfl_xor(v, 4);                                            \
            v += __shfl_xor(v, 8);                                            \
            if (lo == 0) atomicAdd(&dtot[ar + mr * 16 + hi * 4 + rg], v);     \
        }                                                                     \
    }
#define LOAD_AF_RS()                                                          \
    {                                                                         \
        _Pragma("unroll") for (int mr = 0; mr < 4; ++mr) {                    \
            int r16 = (ar + mr * 16 + lo) * 16;                               \
            _Pragma("unroll") for (int kt = 0; kt < 4; ++kt)                  \
                af[kt][mr] = xb8[r16 + kt * 4 + hi];                          \
            _Pragma("unroll") for (int rg = 0; rg < 4; ++rg) rs[mr][rg] = 0.f;\
        }                                                                     \
    }
#define MFMA_GROUP(KT, BG)                                                    \
    _Pragma("unroll") for (int mr = 0; mr < 4; ++mr)                          \
        _Pragma("unroll") for (int nr = 0; nr < 4; ++nr)                      \
            acc[mr][nr] = __builtin_amdgcn_mfma_f32_16x16x32_bf16(            \
                af[KT][mr], (BG)[nr], acc[mr][nr], 0, 0, 0);

    int q = sub;
    int cur_band = (q < n0) ? b0 : b1;
    int j = (q < n0) ? b0 + q : b1 + (q - n0);
    int ar = cur_band * 128 + wm * 64;
    int jr = j * 128 + wn * 64;

    LOAD_AF_RS();
#pragma unroll
    for (int nr = 0; nr < 4; ++nr)
        bgs[0][nr] = xb8[(jr + nr * 16 + lo) * 16 + hi];  // kt0

    while (true) {
        // epilogue operands: issue early, consume late
        float fc[4];
#pragma unroll
        for (int nr = 0; nr < 4; ++nr) fc[nr] = f[jr + nr * 16 + lo];
        floatx4 er4[4];
#pragma unroll
        for (int mr = 0; mr < 4; ++mr)
            er4[mr] = *(const floatx4*)&e[ar + mr * 16 + hi * 4];

        int nq = q + 16;
        bool have_next = (nq < 65);
        int nband = 0, nj = 0, njr = 0;
        if (have_next) {
            nband = (nq < n0) ? b0 : b1;
            nj = (nq < n0) ? b0 + nq : b1 + (nq - n0);
            njr = nj * 128 + wn * 64;
        }

        floatx4 acc[4][4];
#pragma unroll
        for (int mr = 0; mr < 4; ++mr)
#pragma unroll
            for (int nr = 0; nr < 4; ++nr)
                acc[mr][nr] = (floatx4){0.f, 0.f, 0.f, 0.f};

        // pipelined K loop: issue kt+1's loads before kt's MFMAs
#pragma unroll
        for (int nr = 0; nr < 4; ++nr)
            bgs[1][nr] = xb8[(jr + nr * 16 + lo) * 16 + 4 + hi];  // kt1
        MFMA_GROUP(0, bgs[0]);
#pragma unroll
        for (int nr = 0; nr < 4; ++nr)
            bgs[0][nr] = xb8[(jr + nr * 16 + lo) * 16 + 8 + hi];  // kt2
        MFMA_GROUP(1, bgs[1]);
#pragma unroll
        for (int nr = 0; nr < 4; ++nr)
            bgs[1][nr] = xb8[(jr + nr * 16 + lo) * 16 + 12 + hi];  // kt3
        MFMA_GROUP(2, bgs[0]);
        if (have_next && nband == cur_band) {
#pragma unroll
            for (int nr = 0; nr < 4; ++nr)
                bgs[0][nr] = xb8[(njr + nr * 16 + lo) * 16 + hi];  // next kt0
        }
        MFMA_GROUP(3, bgs[1]);

        // epilogue (hides the in-flight next-tile loads)
        float cs[4] = {0.f, 0.f, 0.f, 0.f};
#pragma unroll
        for (int mr = 0; mr < 4; ++mr)
#pragma unroll
            for (int nr = 0; nr < 4; ++nr)
#pragma unroll
                for (int rg = 0; rg < 4; ++rg) {
                    float d2 = fmaf(-2.f, acc[mr][nr][rg], er4[mr][rg] + deps2) + fc[nr];
                    float pp = fmaxf(d2, deps2);
                    float d = pp * __frsqrt_rn(pp);  // sqrt via v_rsq
                    rs[mr][rg] += d;
                    cs[nr] += d;
                }
        if (j != cur_band) {
#pragma unroll
            for (int nr = 0; nr < 4; ++nr) {
                float v = cs[nr];
                v += __shfl_xor(v, 16);
                v += __shfl_xor(v, 32);
                if (hi == 0) atomicAdd(&dtot[jr + nr * 16 + lo], v);
            }
        }

        if (!have_next) break;
        q = nq; j = nj; jr = njr;
        if (nband != cur_band) {  // <=1 per block: flush rows, reload A, restart pipe
            FLUSH_RS();
            cur_band = nband;
            ar = cur_band * 128 + wm * 64;
            LOAD_AF_RS();
#pragma unroll
            for (int nr = 0; nr < 4; ++nr)
                bgs[0][nr] = xb8[(jr + nr * 16 + lo) * 16 + hi];
        }
    }
    FLUSH_RS();
#undef FLUSH_RS
#undef LOAD_AF_RS
#undef MFMA_GROUP
}

// fused feature-loss reduce + final output (single block)
__global__ void __launch_bounds__(1024)
k_featout(const float* __restrict__ ws, float* __restrict__ out) {
    int t = threadIdx.x;
    const float* dtot = ws + OFF_DTOT;
    const float* dpos = ws + OFF_DPOS;
    float r = 0.f;
#pragma unroll
    for (int k = 0; k < B / 1024; k++) {
        int i = k * 1024 + t;
        float dp = dpos[i], dt = dtot[i];
        r += dp / (dt - dp);
    }
    for (int o = 32; o; o >>= 1) r += __shfl_xor(r, o);
    __shared__ float sm[16];
    if ((t & 63) == 0) sm[t >> 6] = r;
    __syncthreads();
    if (t == 0) {
        float lf = 0.f;
#pragma unroll
        for (int w = 0; w < 16; w++) lf += sm[w];
        float la = ws[0] / (float)B;
        out[0] = la + LAMBD * lf;
        out[1] = la;
        out[2] = lf;
    }
}

extern "C" void kernel_launch(void* const* d_in, const int* in_sizes, int n_in,
                              void* d_out, int out_size, void* d_ws, size_t ws_size,
                              hipStream_t stream) {
    const float* data = (const float*)d_in[0];
    const float* x = (const float*)d_in[1];
    const int* y = (const int*)d_in[2];
    float* out = (float*)d_out;
    float* ws = (float*)d_ws;

    (void)hipMemsetAsync(ws + OFF_FO, 0xFF, C * sizeof(unsigned), stream);  // fo
    k_rowstats<<<B / 4, 256, 0, stream>>>(x, y, ws);
    k_ce<<<B / 4, 256, 0, stream>>>(data, y, ws);
    k_dpos<<<B / 4, 256, 0, stream>>>(x, y, ws);
    k_gram_dtot<<<512, 256, 0, stream>>>(ws);
    k_featout<<<1, 1024, 0, stream>>>(ws, out);
}